// Round 1
// baseline (1314.077 us; speedup 1.0000x reference)
//
#include <hip/hip_runtime.h>
#include <hip/hip_bf16.h>
#include <stdint.h>

#define B_     2048
#define WIN_   11
#define K_     4096
#define VOCAB_ 30522
#define NOUT_  18
#define TOPK_  64
#define PI_F   3.14159274101257324f  /* float32(pi), 0x40490FDB */

// ---------------------------------------------------------------------------
// Kernel A: per-batch window prep. owin[b*WIN+w] = {cos(pos), sin(pos), nzf, id-bits}
// ---------------------------------------------------------------------------
__global__ void prep_kernel(const int* __restrict__ ids, float4* __restrict__ owin) {
    int b = blockIdx.x * blockDim.x + threadIdx.x;
    if (b >= B_) return;
    const int* row = ids + b * WIN_;
    int poss[WIN_];
    int cnt = 0;
#pragma unroll
    for (int w = 0; w < WIN_; ++w) {
        int nz = (row[w] != 0);
        cnt += nz;
        poss[w] = cnt;           // inclusive cumsum
    }
    int sl = (cnt > 0) ? cnt : WIN_;
    float fsl = (float)sl;
#pragma unroll
    for (int w = 0; w < WIN_; ++w) {
        float pos = __fdiv_rn(__fmul_rn(PI_F, (float)poss[w]), fsl);
        float4 o;
        o.x = cosf(pos);
        o.y = sinf(pos);
        o.z = (row[w] != 0) ? 1.0f : 0.0f;
        o.w = __int_as_float(row[w]);
        owin[b * WIN_ + w] = o;
    }
}

// ---------------------------------------------------------------------------
// Kernel B: pf^T[k, b] = sum_w (|W[k,id]| + |angle|) * nz
// One block per k -> all gathers stay inside the 244 KB slice W[k,:,:].
// ---------------------------------------------------------------------------
__global__ __launch_bounds__(256) void pf_kernel(const float2* __restrict__ W2,
                                                 const float4* __restrict__ owin,
                                                 float* __restrict__ pfT) {
    const int k = blockIdx.x;
    const float2* Wk = W2 + (size_t)k * VOCAB_;
    for (int b = threadIdx.x; b < B_; b += 256) {
        const float4* ow = owin + b * WIN_;
        float acc = 0.0f;
#pragma unroll
        for (int w = 0; w < WIN_; ++w) {
            float4 o = ow[w];
            int id = __float_as_int(o.w);
            float2 g = Wk[id];
            // |W| : match numpy (mul, mul, add, sqrt - all round-to-nearest, no fma)
            float wabs = sqrtf(__fadd_rn(__fmul_rn(g.x, g.x), __fmul_rn(g.y, g.y)));
            // phis = g * conj(o)
            float pre = __fadd_rn(__fmul_rn(g.x, o.x), __fmul_rn(g.y, o.y));
            float pim = __fsub_rn(__fmul_rn(g.y, o.x), __fmul_rn(g.x, o.y));
            if (pre < 1e-10f && pre > -1e-10f) pre = 1e-10f;
            if (pim < 1e-10f && pim > -1e-10f) pim = 1e-10f;
            float ang = fabsf(atan2f(pim, pre));
            acc = __fadd_rn(acc, __fmul_rn(__fadd_rn(wabs, ang), o.z));
        }
        pfT[(size_t)k * B_ + b] = acc;   // coalesced: consecutive threads -> consecutive b
    }
}

// ---------------------------------------------------------------------------
// Kernel T: transpose [K,B] -> [B,K] via 64x64 LDS tiles
// ---------------------------------------------------------------------------
__global__ __launch_bounds__(256) void transpose_kb(const float* __restrict__ pfT,
                                                    float* __restrict__ pf) {
    __shared__ float tile[64][65];
    int kb = blockIdx.x * 64;   // k base
    int bb = blockIdx.y * 64;   // b base
    int tx = threadIdx.x & 63;
    int ty = threadIdx.x >> 6;  // 0..3
#pragma unroll
    for (int i = 0; i < 64; i += 4)
        tile[ty + i][tx] = pfT[(size_t)(kb + ty + i) * B_ + (bb + tx)];
    __syncthreads();
#pragma unroll
    for (int i = 0; i < 64; i += 4)
        pf[(size_t)(bb + ty + i) * K_ + (kb + tx)] = tile[tx][ty + i];
}

// ---------------------------------------------------------------------------
// Kernel C: per-row exact top-64 (radix select on float bits; all pf >= 0 so
// uint order == float order), jax.lax.top_k tie semantics (lower index first),
// then logits[b,n] = b_out[n] + sum over selected k of w_out[n,k].
// Fully deterministic (no atomics decide ordering).
// ---------------------------------------------------------------------------
__global__ __launch_bounds__(256) void topk_logits_kernel(const float* __restrict__ pf,
                                                          const float* __restrict__ w_out,
                                                          const float* __restrict__ b_out,
                                                          float* __restrict__ out) {
    const int b = blockIdx.x;
    const int t = threadIdx.x;
    __shared__ uint32_t srow[K_];
    __shared__ int hist[256];
    __shared__ uint32_t sh_prefix;
    __shared__ int sh_need;
    __shared__ int wave_gt[4], wave_eq[4];
    __shared__ int gt_running, eq_running;
    __shared__ int idxlist[TOPK_];

    const float* rowp = pf + (size_t)b * K_;
    for (int i = t; i < K_; i += 256) srow[i] = __float_as_uint(rowp[i]);
    if (t == 0) { sh_prefix = 0u; sh_need = TOPK_; gt_running = 0; eq_running = 0; }
    __syncthreads();

    // 4-pass MSB-first radix select: find exact key of the 64th-largest value
    for (int pass = 0; pass < 4; ++pass) {
        int shift = 24 - 8 * pass;
        uint32_t himask = (pass == 0) ? 0u : (0xFFFFFFFFu << (shift + 8));
        hist[t] = 0;
        __syncthreads();
        uint32_t prefix = sh_prefix;
        for (int i = t; i < K_; i += 256) {
            uint32_t u = srow[i];
            if ((u & himask) == prefix) atomicAdd(&hist[(u >> shift) & 255], 1);
        }
        __syncthreads();
        if (t == 0) {
            int need = sh_need, cum = 0, bin = 255;
            for (; bin >= 0; --bin) {
                int c = hist[bin];
                if (cum + c >= need) { sh_need = need - cum; break; }
                cum += c;
            }
            sh_prefix = prefix | ((uint32_t)bin << shift);
        }
        __syncthreads();
    }
    const uint32_t T = sh_prefix;
    const int r = sh_need;            // how many ties (==T) to take, by index order
    const int c_gt = TOPK_ - r;       // count of strictly-greater elements

    // index-ordered selection, deterministic slots
    for (int cbase = 0; cbase < K_; cbase += 256) {
        uint32_t u = srow[cbase + t];
        bool gt = (u > T);
        bool eq = (u == T);
        unsigned long long mg = __ballot(gt);
        unsigned long long me = __ballot(eq);
        int lane = t & 63, wv = t >> 6;
        if (lane == 0) { wave_gt[wv] = __popcll(mg); wave_eq[wv] = __popcll(me); }
        __syncthreads();
        int offg = gt_running, offe = eq_running;
        for (int w2 = 0; w2 < wv; ++w2) { offg += wave_gt[w2]; offe += wave_eq[w2]; }
        unsigned long long lmask = (lane == 0) ? 0ull : ((~0ull) >> (64 - lane));
        int rkg = offg + __popcll(mg & lmask);
        int rke = offe + __popcll(me & lmask);
        if (gt) idxlist[rkg] = cbase + t;
        else if (eq && rke < r) idxlist[c_gt + rke] = cbase + t;
        __syncthreads();
        if (t == 0) {
            gt_running += wave_gt[0] + wave_gt[1] + wave_gt[2] + wave_gt[3];
            eq_running += wave_eq[0] + wave_eq[1] + wave_eq[2] + wave_eq[3];
        }
        __syncthreads();
    }

    if (t < NOUT_) {
        float s = b_out[t];
        const float* wrow = w_out + (size_t)t * K_;
#pragma unroll 8
        for (int j = 0; j < TOPK_; ++j) s += wrow[idxlist[j]];
        out[b * NOUT_ + t] = s;
    }
}

// ---------------------------------------------------------------------------
extern "C" void kernel_launch(void* const* d_in, const int* in_sizes, int n_in,
                              void* d_out, int out_size, void* d_ws, size_t ws_size,
                              hipStream_t stream) {
    const int*   ids   = (const int*)d_in[0];
    const float* W     = (const float*)d_in[1];
    const float* w_out = (const float*)d_in[2];
    const float* b_out = (const float*)d_in[3];
    float* out = (float*)d_out;

    char* ws = (char*)d_ws;
    const size_t pf_bytes = (size_t)K_ * B_ * sizeof(float);  // 33.55 MB
    float*  pfT  = (float*)(ws);                    // [K, B]
    float*  pf   = (float*)(ws + pf_bytes);         // [B, K]
    float4* owin = (float4*)(ws + 2 * pf_bytes);    // [B*WIN] float4 (~360 KB)

    prep_kernel<<<(B_ + 255) / 256, 256, 0, stream>>>(ids, owin);
    pf_kernel<<<K_, 256, 0, stream>>>((const float2*)W, owin, pfT);
    transpose_kb<<<dim3(K_ / 64, B_ / 64), 256, 0, stream>>>(pfT, pf);
    topk_logits_kernel<<<B_, 256, 0, stream>>>(pf, w_out, b_out, out);
}

// Round 2
// 845.052 us; speedup vs baseline: 1.5550x; 1.5550x over previous
//
#include <hip/hip_runtime.h>
#include <hip/hip_bf16.h>
#include <stdint.h>

#define B_     2048
#define WIN_   11
#define K_     4096
#define VOCAB_ 30522
#define NOUT_  18
#define TOPK_  64
#define PI_F   3.14159274101257324f  /* float32(pi) */

#define NCHUNK_ 3
#define CHUNK_  10176              /* 3*10176 = 30528 >= VOCAB_ */
#define PFTH_   512
#define NB_     4                  /* B_/PFTH_ rows per thread */
#define SMEM_BYTES_ (2 * CHUNK_ * 8)   /* 162816 B < 160 KiB */

// ---------------------------------------------------------------------------
// Kernel A: per-batch window prep -> cos/sin per (b,w)
// ---------------------------------------------------------------------------
__global__ void prep_kernel(const int* __restrict__ ids, float2* __restrict__ ocs) {
    int b = blockIdx.x * blockDim.x + threadIdx.x;
    if (b >= B_) return;
    const int* row = ids + b * WIN_;
    int poss[WIN_];
    int cnt = 0;
#pragma unroll
    for (int w = 0; w < WIN_; ++w) { cnt += (row[w] != 0); poss[w] = cnt; }
    float fsl = (float)((cnt > 0) ? cnt : WIN_);
#pragma unroll
    for (int w = 0; w < WIN_; ++w) {
        float pos = __fdiv_rn(__fmul_rn(PI_F, (float)poss[w]), fsl);
        float2 o;
        o.x = cosf(pos);
        o.y = sinf(pos);
        ocs[b * WIN_ + w] = o;
    }
}

// ---------------------------------------------------------------------------
// Kernel B: pf^T[k, b] = sum_w (|W[k,id]| + |angle|) * nz
// One block per k. The 244 KB slice W[k,:,:] is streamed (coalesced) into LDS
// in 3 chunks (double-buffered, global_load_lds width-16, issue-early so the
// next chunk loads under the current chunk's compute). Gathers hit LDS.
// Per-(b,w) contribution kept in a register slot written exactly once across
// chunks; final sum in exact w order -> bit-identical to reference path.
// ---------------------------------------------------------------------------
__global__ __launch_bounds__(PFTH_, 2) void pf_kernel(const float2* __restrict__ W2,
                                                      const float2* __restrict__ ocs,
                                                      const int* __restrict__ idsg,
                                                      float* __restrict__ pfT) {
    extern __shared__ char smem[];
    float2* sbuf = (float2*)smem;          // [2][CHUNK_]

    const int k = blockIdx.x;
    const int t = threadIdx.x;
    const int wv = t >> 6;                 // wave id 0..7
    const float2* Wk = W2 + (size_t)k * VOCAB_;

    // preload ids and cos/sin for this thread's NB_ batch rows
    int   id[NB_][WIN_];
    float oc[NB_][WIN_], os[NB_][WIN_];
#pragma unroll
    for (int i = 0; i < NB_; ++i) {
        int b = i * PFTH_ + t;
#pragma unroll
        for (int w = 0; w < WIN_; ++w) {
            id[i][w] = idsg[b * WIN_ + w];
            float2 o = ocs[b * WIN_ + w];
            oc[i][w] = o.x;
            os[i][w] = o.y;
        }
    }
    float c[NB_][WIN_];
#pragma unroll
    for (int i = 0; i < NB_; ++i)
#pragma unroll
        for (int w = 0; w < WIN_; ++w) c[i][w] = 0.0f;

    // stage chunk cc into LDS buffer `buf` (wave-uniform LDS base + lane*16)
    auto stage = [&](int cc, int buf) {
        const int base = cc * CHUNK_;
        int ent = VOCAB_ - base; if (ent > CHUNK_) ent = CHUNK_;
        const int n16 = (ent + 1) >> 1;                 // 16-byte units
        const char* gsrc = (const char*)(Wk + base);
        char* lbase = (char*)(sbuf + (size_t)buf * CHUNK_);
#pragma unroll
        for (int j = 0; j < (CHUNK_ / 2 + PFTH_ - 1) / PFTH_; ++j) {   // 10 iters
            int e = j * PFTH_ + t;
            if (e < n16) {
                __builtin_amdgcn_global_load_lds(
                    (const __attribute__((address_space(1))) void*)(gsrc + (size_t)e * 16),
                    (__attribute__((address_space(3))) void*)(lbase + ((size_t)(j * PFTH_ + wv * 64)) * 16),
                    16, 0, 0);
            }
        }
    };

    stage(0, 0);
#pragma unroll 1
    for (int cc = 0; cc < NCHUNK_; ++cc) {
        __syncthreads();                       // drains: chunk cc staged; other buf free
        if (cc + 1 < NCHUNK_) stage(cc + 1, (cc + 1) & 1);
        const float2* sb = sbuf + (size_t)(cc & 1) * CHUNK_;
        const int lo = cc * CHUNK_;
#pragma unroll
        for (int i = 0; i < NB_; ++i) {
#pragma unroll
            for (int w = 0; w < WIN_; ++w) {
                int rel = id[i][w] - lo;
                if ((unsigned)rel < (unsigned)CHUNK_) {
                    float2 g = sb[rel];
                    float wabs = sqrtf(__fadd_rn(__fmul_rn(g.x, g.x), __fmul_rn(g.y, g.y)));
                    float pre = __fadd_rn(__fmul_rn(g.x, oc[i][w]), __fmul_rn(g.y, os[i][w]));
                    float pim = __fsub_rn(__fmul_rn(g.y, oc[i][w]), __fmul_rn(g.x, os[i][w]));
                    if (pre < 1e-10f && pre > -1e-10f) pre = 1e-10f;
                    if (pim < 1e-10f && pim > -1e-10f) pim = 1e-10f;
                    float ang = fabsf(atan2f(pim, pre));
                    c[i][w] = (id[i][w] != 0) ? __fadd_rn(wabs, ang) : 0.0f;
                }
            }
        }
    }

    float* outp = pfT + (size_t)k * B_;
#pragma unroll
    for (int i = 0; i < NB_; ++i) {
        float acc = 0.0f;
#pragma unroll
        for (int w = 0; w < WIN_; ++w) acc = __fadd_rn(acc, c[i][w]);
        outp[i * PFTH_ + t] = acc;             // coalesced across threads
    }
}

// ---------------------------------------------------------------------------
// Kernel T: transpose [K,B] -> [B,K] via 64x64 LDS tiles
// ---------------------------------------------------------------------------
__global__ __launch_bounds__(256) void transpose_kb(const float* __restrict__ pfT,
                                                    float* __restrict__ pf) {
    __shared__ float tile[64][65];
    int kb = blockIdx.x * 64;
    int bb = blockIdx.y * 64;
    int tx = threadIdx.x & 63;
    int ty = threadIdx.x >> 6;
#pragma unroll
    for (int i = 0; i < 64; i += 4)
        tile[ty + i][tx] = pfT[(size_t)(kb + ty + i) * B_ + (bb + tx)];
    __syncthreads();
#pragma unroll
    for (int i = 0; i < 64; i += 4)
        pf[(size_t)(bb + ty + i) * K_ + (kb + tx)] = tile[tx][ty + i];
}

// ---------------------------------------------------------------------------
// Kernel C: per-row exact top-64 (radix select, jax tie semantics) + logits
// ---------------------------------------------------------------------------
__global__ __launch_bounds__(256) void topk_logits_kernel(const float* __restrict__ pf,
                                                          const float* __restrict__ w_out,
                                                          const float* __restrict__ b_out,
                                                          float* __restrict__ out) {
    const int b = blockIdx.x;
    const int t = threadIdx.x;
    __shared__ uint32_t srow[K_];
    __shared__ int hist[256];
    __shared__ uint32_t sh_prefix;
    __shared__ int sh_need;
    __shared__ int wave_gt[4], wave_eq[4];
    __shared__ int gt_running, eq_running;
    __shared__ int idxlist[TOPK_];

    const float* rowp = pf + (size_t)b * K_;
    for (int i = t; i < K_; i += 256) srow[i] = __float_as_uint(rowp[i]);
    if (t == 0) { sh_prefix = 0u; sh_need = TOPK_; gt_running = 0; eq_running = 0; }
    __syncthreads();

    for (int pass = 0; pass < 4; ++pass) {
        int shift = 24 - 8 * pass;
        uint32_t himask = (pass == 0) ? 0u : (0xFFFFFFFFu << (shift + 8));
        hist[t] = 0;
        __syncthreads();
        uint32_t prefix = sh_prefix;
        for (int i = t; i < K_; i += 256) {
            uint32_t u = srow[i];
            if ((u & himask) == prefix) atomicAdd(&hist[(u >> shift) & 255], 1);
        }
        __syncthreads();
        if (t == 0) {
            int need = sh_need, cum = 0, bin = 255;
            for (; bin >= 0; --bin) {
                int c = hist[bin];
                if (cum + c >= need) { sh_need = need - cum; break; }
                cum += c;
            }
            sh_prefix = prefix | ((uint32_t)bin << shift);
        }
        __syncthreads();
    }
    const uint32_t T = sh_prefix;
    const int r = sh_need;
    const int c_gt = TOPK_ - r;

    for (int cbase = 0; cbase < K_; cbase += 256) {
        uint32_t u = srow[cbase + t];
        bool gt = (u > T);
        bool eq = (u == T);
        unsigned long long mg = __ballot(gt);
        unsigned long long me = __ballot(eq);
        int lane = t & 63, wv = t >> 6;
        if (lane == 0) { wave_gt[wv] = __popcll(mg); wave_eq[wv] = __popcll(me); }
        __syncthreads();
        int offg = gt_running, offe = eq_running;
        for (int w2 = 0; w2 < wv; ++w2) { offg += wave_gt[w2]; offe += wave_eq[w2]; }
        unsigned long long lmask = (lane == 0) ? 0ull : ((~0ull) >> (64 - lane));
        int rkg = offg + __popcll(mg & lmask);
        int rke = offe + __popcll(me & lmask);
        if (gt) idxlist[rkg] = cbase + t;
        else if (eq && rke < r) idxlist[c_gt + rke] = cbase + t;
        __syncthreads();
        if (t == 0) {
            gt_running += wave_gt[0] + wave_gt[1] + wave_gt[2] + wave_gt[3];
            eq_running += wave_eq[0] + wave_eq[1] + wave_eq[2] + wave_eq[3];
        }
        __syncthreads();
    }

    if (t < NOUT_) {
        float s = b_out[t];
        const float* wrow = w_out + (size_t)t * K_;
#pragma unroll 8
        for (int j = 0; j < TOPK_; ++j) s += wrow[idxlist[j]];
        out[b * NOUT_ + t] = s;
    }
}

// ---------------------------------------------------------------------------
extern "C" void kernel_launch(void* const* d_in, const int* in_sizes, int n_in,
                              void* d_out, int out_size, void* d_ws, size_t ws_size,
                              hipStream_t stream) {
    const int*   ids   = (const int*)d_in[0];
    const float* W     = (const float*)d_in[1];
    const float* w_out = (const float*)d_in[2];
    const float* b_out = (const float*)d_in[3];
    float* out = (float*)d_out;

    char* ws = (char*)d_ws;
    const size_t pf_bytes = (size_t)K_ * B_ * sizeof(float);  // 33.55 MB
    float*  pfT = (float*)(ws);                    // [K, B]
    float*  pf  = (float*)(ws + pf_bytes);         // [B, K]
    float2* ocs = (float2*)(ws + 2 * pf_bytes);    // [B*WIN] float2 (~180 KB)

    // raise dynamic LDS cap for pf_kernel (first call is outside graph capture,
    // attribute persists; call is idempotent and not a stream op)
    (void)hipFuncSetAttribute((const void*)pf_kernel,
                              hipFuncAttributeMaxDynamicSharedMemorySize,
                              SMEM_BYTES_);

    prep_kernel<<<(B_ + 255) / 256, 256, 0, stream>>>(ids, ocs);
    pf_kernel<<<K_, PFTH_, SMEM_BYTES_, stream>>>((const float2*)W, ocs, ids, pfT);
    transpose_kb<<<dim3(K_ / 64, B_ / 64), 256, 0, stream>>>(pfT, pf);
    topk_logits_kernel<<<B_, 256, 0, stream>>>(pf, w_out, b_out, out);
}

// Round 3
// 521.036 us; speedup vs baseline: 2.5220x; 1.6219x over previous
//
#include <hip/hip_runtime.h>
#include <hip/hip_bf16.h>
#include <stdint.h>

#define B_     2048
#define WIN_   11
#define K_     4096
#define VOCAB_ 30522
#define NOUT_  18
#define TOPK_  64
#define NPAIR_ (B_ * WIN_)         /* 22528 */
#define PI_F   3.14159274101257324f

#define NCHUNK_ 7
#define CHUNK_  4544               /* 7*4544 = 31808 >= VOCAB_ */
#define PFTH_   1024
#define PCON_BYTES_ (NPAIR_ * 4)              /* 90112 */
#define SMEM_BYTES_ (PCON_BYTES_ + 2 * CHUNK_ * 8)  /* 162816 B (proven size) */

// ---------------------------------------------------------------------------
// Kernel A: per-batch window prep -> cos/sin per (b,w)
// ---------------------------------------------------------------------------
__global__ void prep_kernel(const int* __restrict__ ids, float2* __restrict__ ocs) {
    int b = blockIdx.x * blockDim.x + threadIdx.x;
    if (b >= B_) return;
    const int* row = ids + b * WIN_;
    int poss[WIN_];
    int cnt = 0;
#pragma unroll
    for (int w = 0; w < WIN_; ++w) { cnt += (row[w] != 0); poss[w] = cnt; }
    float fsl = (float)((cnt > 0) ? cnt : WIN_);
#pragma unroll
    for (int w = 0; w < WIN_; ++w) {
        float pos = __fdiv_rn(__fmul_rn(PI_F, (float)poss[w]), fsl);
        float2 o;
        o.x = cosf(pos);
        o.y = sinf(pos);
        ocs[b * WIN_ + w] = o;
    }
}

// ---------------------------------------------------------------------------
// Kernel A2: stable deterministic bucket-by-chunk of the 22528 (b,w) pairs.
// Single block, 512 threads, strided ownership (coalesced), two-level scan.
// Output: smeta[pos] = {id, pairidx, cos, sin}; chunkstart[0..7].
// ---------------------------------------------------------------------------
__global__ __launch_bounds__(512) void bucket_kernel(const int* __restrict__ ids,
                                                     const float2* __restrict__ ocs,
                                                     float4* __restrict__ smeta,
                                                     int* __restrict__ chunkstart) {
    __shared__ int lcnt[512 * NCHUNK_];   // [thread][bucket] count -> excl prefix
    __shared__ int segtot[NCHUNK_][8];
    __shared__ int tot[NCHUNK_];
    __shared__ int bbase[NCHUNK_ + 1];
    const int t = threadIdx.x;

#pragma unroll
    for (int c = 0; c < NCHUNK_; ++c) lcnt[t * NCHUNK_ + c] = 0;
    __syncthreads();

    // pass 1: count per (thread, bucket)
    for (int p = t; p < NPAIR_; p += 512) {
        int id = ids[p];
        if (id != 0) lcnt[t * NCHUNK_ + (id / CHUNK_)] += 1;
    }
    __syncthreads();

    // two-level exclusive scan of the 512 per-thread counts, per bucket
    if (t < NCHUNK_ * 8) {                 // 56 threads: (bucket, segment of 64)
        int bkt = t >> 3, seg = t & 7;
        int run = 0;
        for (int i = 0; i < 64; ++i) {
            int idx = (seg * 64 + i) * NCHUNK_ + bkt;
            int tmp = lcnt[idx];
            lcnt[idx] = run;
            run += tmp;
        }
        segtot[bkt][seg] = run;
    }
    __syncthreads();
    if (t < NCHUNK_) {                     // scan segments within bucket
        int run = 0;
#pragma unroll
        for (int s = 0; s < 8; ++s) { int tmp = segtot[t][s]; segtot[t][s] = run; run += tmp; }
        tot[t] = run;
    }
    __syncthreads();
    if (t == 0) {                          // bucket bases
        int run = 0;
#pragma unroll
        for (int c = 0; c < NCHUNK_; ++c) { bbase[c] = run; run += tot[c]; }
        bbase[NCHUNK_] = run;
#pragma unroll
        for (int c = 0; c <= NCHUNK_; ++c) chunkstart[c] = bbase[c];
    }
    __syncthreads();
    if (t < NCHUNK_ * 8) {                 // add segment base into per-thread prefixes
        int bkt = t >> 3, seg = t & 7;
        int add = segtot[bkt][seg];
        for (int i = 0; i < 64; ++i) lcnt[(seg * 64 + i) * NCHUNK_ + bkt] += add;
    }
    __syncthreads();

    // pass 2: scatter (deterministic: disjoint reserved ranges per thread)
    for (int p = t; p < NPAIR_; p += 512) {
        int id = ids[p];
        if (id == 0) continue;
        int bkt = id / CHUNK_;
        int pos = bbase[bkt] + lcnt[t * NCHUNK_ + bkt];
        lcnt[t * NCHUNK_ + bkt] += 1;
        float2 o = ocs[p];
        float4 m;
        m.x = __int_as_float(id);
        m.y = __int_as_float(p);           // dst slot = b*WIN + w
        m.z = o.x;
        m.w = o.y;
        smeta[pos] = m;
    }
}

// ---------------------------------------------------------------------------
// Kernel B: pf^T[k, b]. One block per k; W[k] slice streamed into LDS in 7
// double-buffered chunks (global_load_lds w16, issue-early). Pairs bucketed
// by chunk -> each pair computed EXACTLY once, no divergent membership test.
// Contribution -> LDS pcontrib[pairidx]; final per-b sum in exact w order.
// ---------------------------------------------------------------------------
__global__ __launch_bounds__(PFTH_, 1) void pf_kernel(const float2* __restrict__ W2,
                                                      const float4* __restrict__ smeta,
                                                      const int* __restrict__ chunkstart,
                                                      float* __restrict__ pfT) {
    extern __shared__ char smem[];
    float* pcontrib = (float*)smem;                       // [NPAIR_]
    float2* sbuf = (float2*)(smem + PCON_BYTES_);         // [2][CHUNK_]

    const int k = blockIdx.x;
    const int t = threadIdx.x;
    const int wv = t >> 6;
    const float2* Wk = W2 + (size_t)k * VOCAB_;

    for (int i = t; i < NPAIR_; i += PFTH_) pcontrib[i] = 0.0f;

    auto stage = [&](int cc, int buf) {
        const int base = cc * CHUNK_;
        int ent = VOCAB_ - base; if (ent > CHUNK_) ent = CHUNK_;
        const int n16 = (ent + 1) >> 1;
        const char* gsrc = (const char*)(Wk + base);
        char* lbase = (char*)(sbuf + (size_t)buf * CHUNK_);
#pragma unroll
        for (int j = 0; j < (CHUNK_ / 2 + PFTH_ - 1) / PFTH_; ++j) {   // 3 iters
            int e = j * PFTH_ + t;
            if (e < n16) {
                __builtin_amdgcn_global_load_lds(
                    (const __attribute__((address_space(1))) void*)(gsrc + (size_t)e * 16),
                    (__attribute__((address_space(3))) void*)(lbase + ((size_t)(j * PFTH_ + wv * 64)) * 16),
                    16, 0, 0);
            }
        }
    };

    stage(0, 0);
#pragma unroll 1
    for (int cc = 0; cc < NCHUNK_; ++cc) {
        __syncthreads();                   // chunk cc staged; prev compute done
        if (cc + 1 < NCHUNK_) stage(cc + 1, (cc + 1) & 1);
        const int start = chunkstart[cc];
        const int end   = chunkstart[cc + 1];
        const float2* sb = sbuf + (size_t)(cc & 1) * CHUNK_;
        const int lo = cc * CHUNK_;
        for (int p = start + t; p < end; p += PFTH_) {
            float4 m = smeta[p];
            int id  = __float_as_int(m.x);
            int dst = __float_as_int(m.y);
            float2 g = sb[id - lo];
            float wabs = sqrtf(__fadd_rn(__fmul_rn(g.x, g.x), __fmul_rn(g.y, g.y)));
            float pre = __fadd_rn(__fmul_rn(g.x, m.z), __fmul_rn(g.y, m.w));
            float pim = __fsub_rn(__fmul_rn(g.y, m.z), __fmul_rn(g.x, m.w));
            if (pre < 1e-10f && pre > -1e-10f) pre = 1e-10f;
            if (pim < 1e-10f && pim > -1e-10f) pim = 1e-10f;
            float ang = fabsf(atan2f(pim, pre));
            pcontrib[dst] = __fadd_rn(wabs, ang);
        }
    }
    __syncthreads();

    float* outp = pfT + (size_t)k * B_;
#pragma unroll
    for (int i = 0; i < B_ / PFTH_; ++i) {   // 2 rows per thread
        int b = i * PFTH_ + t;
        float acc = 0.0f;
#pragma unroll
        for (int w = 0; w < WIN_; ++w)
            acc = __fadd_rn(acc, pcontrib[b * WIN_ + w]);
        outp[b] = acc;                        // coalesced
    }
}

// ---------------------------------------------------------------------------
// Kernel T: transpose [K,B] -> [B,K] via 64x64 LDS tiles
// ---------------------------------------------------------------------------
__global__ __launch_bounds__(256) void transpose_kb(const float* __restrict__ pfT,
                                                    float* __restrict__ pf) {
    __shared__ float tile[64][65];
    int kb = blockIdx.x * 64;
    int bb = blockIdx.y * 64;
    int tx = threadIdx.x & 63;
    int ty = threadIdx.x >> 6;
#pragma unroll
    for (int i = 0; i < 64; i += 4)
        tile[ty + i][tx] = pfT[(size_t)(kb + ty + i) * B_ + (bb + tx)];
    __syncthreads();
#pragma unroll
    for (int i = 0; i < 64; i += 4)
        pf[(size_t)(bb + ty + i) * K_ + (kb + tx)] = tile[tx][ty + i];
}

// ---------------------------------------------------------------------------
// Kernel C: per-row exact top-64 (radix select, jax tie semantics) + logits
// ---------------------------------------------------------------------------
__global__ __launch_bounds__(256) void topk_logits_kernel(const float* __restrict__ pf,
                                                          const float* __restrict__ w_out,
                                                          const float* __restrict__ b_out,
                                                          float* __restrict__ out) {
    const int b = blockIdx.x;
    const int t = threadIdx.x;
    __shared__ uint32_t srow[K_];
    __shared__ int hist[256];
    __shared__ uint32_t sh_prefix;
    __shared__ int sh_need;
    __shared__ int wave_gt[4], wave_eq[4];
    __shared__ int gt_running, eq_running;
    __shared__ int idxlist[TOPK_];

    const float* rowp = pf + (size_t)b * K_;
    for (int i = t; i < K_; i += 256) srow[i] = __float_as_uint(rowp[i]);
    if (t == 0) { sh_prefix = 0u; sh_need = TOPK_; gt_running = 0; eq_running = 0; }
    __syncthreads();

    for (int pass = 0; pass < 4; ++pass) {
        int shift = 24 - 8 * pass;
        uint32_t himask = (pass == 0) ? 0u : (0xFFFFFFFFu << (shift + 8));
        hist[t] = 0;
        __syncthreads();
        uint32_t prefix = sh_prefix;
        for (int i = t; i < K_; i += 256) {
            uint32_t u = srow[i];
            if ((u & himask) == prefix) atomicAdd(&hist[(u >> shift) & 255], 1);
        }
        __syncthreads();
        if (t == 0) {
            int need = sh_need, cum = 0, bin = 255;
            for (; bin >= 0; --bin) {
                int c = hist[bin];
                if (cum + c >= need) { sh_need = need - cum; break; }
                cum += c;
            }
            sh_prefix = prefix | ((uint32_t)bin << shift);
        }
        __syncthreads();
    }
    const uint32_t T = sh_prefix;
    const int r = sh_need;
    const int c_gt = TOPK_ - r;

    for (int cbase = 0; cbase < K_; cbase += 256) {
        uint32_t u = srow[cbase + t];
        bool gt = (u > T);
        bool eq = (u == T);
        unsigned long long mg = __ballot(gt);
        unsigned long long me = __ballot(eq);
        int lane = t & 63, wv = t >> 6;
        if (lane == 0) { wave_gt[wv] = __popcll(mg); wave_eq[wv] = __popcll(me); }
        __syncthreads();
        int offg = gt_running, offe = eq_running;
        for (int w2 = 0; w2 < wv; ++w2) { offg += wave_gt[w2]; offe += wave_eq[w2]; }
        unsigned long long lmask = (lane == 0) ? 0ull : ((~0ull) >> (64 - lane));
        int rkg = offg + __popcll(mg & lmask);
        int rke = offe + __popcll(me & lmask);
        if (gt) idxlist[rkg] = cbase + t;
        else if (eq && rke < r) idxlist[c_gt + rke] = cbase + t;
        __syncthreads();
        if (t == 0) {
            gt_running += wave_gt[0] + wave_gt[1] + wave_gt[2] + wave_gt[3];
            eq_running += wave_eq[0] + wave_eq[1] + wave_eq[2] + wave_eq[3];
        }
        __syncthreads();
    }

    if (t < NOUT_) {
        float s = b_out[t];
        const float* wrow = w_out + (size_t)t * K_;
#pragma unroll 8
        for (int j = 0; j < TOPK_; ++j) s += wrow[idxlist[j]];
        out[b * NOUT_ + t] = s;
    }
}

// ---------------------------------------------------------------------------
extern "C" void kernel_launch(void* const* d_in, const int* in_sizes, int n_in,
                              void* d_out, int out_size, void* d_ws, size_t ws_size,
                              hipStream_t stream) {
    const int*   ids   = (const int*)d_in[0];
    const float* W     = (const float*)d_in[1];
    const float* w_out = (const float*)d_in[2];
    const float* b_out = (const float*)d_in[3];
    float* out = (float*)d_out;

    char* ws = (char*)d_ws;
    const size_t pf_bytes = (size_t)K_ * B_ * sizeof(float);   // 33.55 MB
    float*  pfT   = (float*)(ws);                              // [K, B]
    float*  pf    = (float*)(ws + pf_bytes);                   // [B, K]
    float2* ocs   = (float2*)(ws + 2 * pf_bytes);              // [NPAIR_] (180 KB)
    float4* smeta = (float4*)(ws + 2 * pf_bytes + 256 * 1024); // [NPAIR_] (360 KB)
    int* chunkstart = (int*)(ws + 2 * pf_bytes + 768 * 1024);  // [8]

    (void)hipFuncSetAttribute((const void*)pf_kernel,
                              hipFuncAttributeMaxDynamicSharedMemorySize,
                              SMEM_BYTES_);

    prep_kernel<<<(B_ + 255) / 256, 256, 0, stream>>>(ids, ocs);
    bucket_kernel<<<1, 512, 0, stream>>>(ids, ocs, smeta, chunkstart);
    pf_kernel<<<K_, PFTH_, SMEM_BYTES_, stream>>>((const float2*)W, smeta, chunkstart, pfT);
    transpose_kb<<<dim3(K_ / 64, B_ / 64), 256, 0, stream>>>(pfT, pf);
    topk_logits_kernel<<<B_, 256, 0, stream>>>(pf, w_out, b_out, out);
}